// Round 16
// baseline (102.661 us; speedup 1.0000x reference)
//
#include <hip/hip_runtime.h>

typedef __attribute__((ext_vector_type(8))) short short8;
typedef __attribute__((ext_vector_type(4))) float f32x4;
typedef __attribute__((ext_vector_type(4))) unsigned int uint4v;

#define HW 32
#define L 1024        // HW*HW
#define C_IN 256
#define BATCH 8
#define NQ 1156       // 34*34 extended grid

static __device__ __forceinline__ unsigned short f2bf(float f){
  unsigned int u = __float_as_uint(f);
  unsigned int r = (u + 0x7FFFu + ((u >> 16) & 1u)) >> 16;   // RNE (no NaN inputs)
  return (unsigned short)r;
}
static __device__ __forceinline__ float bf2f(unsigned short h){
  return __uint_as_float(((unsigned int)h) << 16);
}

#define GLDS16(g, l) __builtin_amdgcn_global_load_lds(                          \
    (const __attribute__((address_space(1))) void*)(g),                         \
    (__attribute__((address_space(3))) void*)(l), 16, 0, 0)

// ---------------- D1: vectorized transposes + moment partials + Wr prep ---------
__global__ __launch_bounds__(256) void fused_prep(const float* __restrict__ fg,
                                                  const float* __restrict__ bgd,
                                                  const float* __restrict__ mask,
                                                  unsigned short* __restrict__ fgT,
                                                  unsigned short* __restrict__ mbgT,
                                                  unsigned short* __restrict__ mbgS,
                                                  float* __restrict__ psum,
                                                  const float* __restrict__ conv_w,
                                                  unsigned short* __restrict__ Wr,
                                                  unsigned short* __restrict__ zpage){
  __shared__ float T[64][65];
  int blk = blockIdx.x;
  if (blk >= 512){
    if (blk == 512) zpage[threadIdx.x] = 0;    // 512 B zero page
    int idx = (blk - 512) * 256 + threadIdx.x; // 589824 Wr elements
    int c = idx & 255;
    int rest = idx >> 8;
    int n = rest & 63;
    int sg = rest >> 6;
    int s = sg % 9, g = sg / 9;
    Wr[idx] = f2bf(conv_w[(((size_t)(g * 64 + n)) * C_IN + c) * 9 + s]);
    return;
  }
  const int NP = BATCH * L;
  int bx = blk & 15, cb = (blk >> 4) & 3, b = blk >> 6;
  int p0 = bx * 64, c0 = cb * 64;
  int tid = threadIdx.x;
  int rr = tid >> 4, px = (tid & 15) * 4;      // read-phase coords
  int cx = tid & 15, ppb = tid >> 4;           // write-phase coords
  const float* F = fg  + ((size_t)b * C_IN + c0) * L + p0;
  const float* G = bgd + ((size_t)b * C_IN + c0) * L + p0;

  #pragma unroll
  for (int it = 0; it < 4; it++){
    int cc = it * 16 + rr;
    float4 v = *(const float4*)(F + (size_t)cc * L + px);
    T[cc][px] = v.x; T[cc][px + 1] = v.y; T[cc][px + 2] = v.z; T[cc][px + 3] = v.w;
  }
  __syncthreads();
  #pragma unroll
  for (int it = 0; it < 4; it++){
    int pp = it * 16 + ppb;
    float t0 = T[cx * 4][pp], t1 = T[cx * 4 + 1][pp], t2 = T[cx * 4 + 2][pp], t3 = T[cx * 4 + 3][pp];
    ushort4 o; o.x = f2bf(t0); o.y = f2bf(t1); o.z = f2bf(t2); o.w = f2bf(t3);
    *(ushort4*)&fgT[(size_t)(b * L + p0 + pp) * C_IN + c0 + cx * 4] = o;
    float s = t0 + t1 + t2 + t3;
    #pragma unroll
    for (int off = 8; off; off >>= 1) s += __shfl_xor(s, off, 16);
    if (cx == 0) psum[(size_t)(cb * 3 + 0) * NP + b * L + p0 + pp] = s;
  }
  __syncthreads();

  float4 mv = *(const float4*)(mask + p0 + px);
  mv.x = 1.f - mv.x; mv.y = 1.f - mv.y; mv.z = 1.f - mv.z; mv.w = 1.f - mv.w;
  #pragma unroll
  for (int it = 0; it < 4; it++){
    int cc = it * 16 + rr;
    float4 v = *(const float4*)(G + (size_t)cc * L + px);
    v.x *= mv.x; v.y *= mv.y; v.z *= mv.z; v.w *= mv.w;
    T[cc][px] = v.x; T[cc][px + 1] = v.y; T[cc][px + 2] = v.z; T[cc][px + 3] = v.w;
    ushort4 o; o.x = f2bf(v.x); o.y = f2bf(v.y); o.z = f2bf(v.z); o.w = f2bf(v.w);
    *(ushort4*)&mbgS[((size_t)b * C_IN + c0 + cc) * L + p0 + px] = o;
  }
  __syncthreads();
  #pragma unroll
  for (int it = 0; it < 4; it++){
    int pp = it * 16 + ppb;
    float t0 = T[cx * 4][pp], t1 = T[cx * 4 + 1][pp], t2 = T[cx * 4 + 2][pp], t3 = T[cx * 4 + 3][pp];
    ushort4 o; o.x = f2bf(t0); o.y = f2bf(t1); o.z = f2bf(t2); o.w = f2bf(t3);
    *(ushort4*)&mbgT[(size_t)(b * L + p0 + pp) * C_IN + c0 + cx * 4] = o;
    float s1 = t0 + t1 + t2 + t3;
    float s2 = t0 * t0 + t1 * t1 + t2 * t2 + t3 * t3;
    #pragma unroll
    for (int off = 8; off; off >>= 1){
      s1 += __shfl_xor(s1, off, 16);
      s2 += __shfl_xor(s2, off, 16);
    }
    if (cx == 0){
      psum[(size_t)(cb * 3 + 1) * NP + b * L + p0 + pp] = s1;
      psum[(size_t)(cb * 3 + 2) * NP + b * L + p0 + pp] = s2;
    }
  }
}

// ---------------- D2: gemm_d (512 thr, 8 waves) + rn/eps tail blocks ------------
__global__ __launch_bounds__(512) void gemm_d_rn(const unsigned short* __restrict__ fgT,
                                                 const unsigned short* __restrict__ mbgT,
                                                 unsigned short* __restrict__ D,
                                                 const float* __restrict__ psum,
                                                 float* __restrict__ rn,
                                                 float* __restrict__ eps){
  __shared__ unsigned short As[64][256];   // 32 KB
  __shared__ unsigned short Bs[64][256];   // 32 KB
  int bid = blockIdx.x;
  if (bid >= 2048){
    int idx = (bid - 2048) * 512 + threadIdx.x;  // 8192 over 16 blocks
    int b = idx >> 10, l = idx & 1023;
    int ly = l >> 5, lx = l & 31;
    const int NP = BATCH * L;
    float n2 = 2.304e-11f;                       // 2304 * 1e-14
    #pragma unroll
    for (int s = 0; s < 9; s++){
      int y = ly + s / 3 - 1, x = lx + s % 3 - 1;
      if ((unsigned)y < HW && (unsigned)x < HW){
        int q = b * L + y * HW + x;
        float s1 = 0.f, s2 = 0.f;
        #pragma unroll
        for (int k = 0; k < 4; k++){
          s1 += psum[(size_t)(k * 3 + 1) * NP + q];
          s2 += psum[(size_t)(k * 3 + 2) * NP + q];
        }
        n2 += s2 + 2e-7f * s1;
      }
    }
    rn[idx] = 1.f / sqrtf(n2);
    float ev = 0.f;
    const int tw[5] = {1, 2, 3, 2, 1};
    #pragma unroll
    for (int oy = -2; oy <= 2; oy++)
      #pragma unroll
      for (int ox = -2; ox <= 2; ox++){
        int y = ly + oy, x = lx + ox;
        if ((unsigned)y < HW && (unsigned)x < HW){
          int q = b * L + y * HW + x;
          float s0 = 0.f;
          #pragma unroll
          for (int k = 0; k < 4; k++) s0 += psum[(size_t)(k * 3 + 0) * NP + q];
          ev += (float)(tw[oy + 2] * tw[ox + 2]) * s0;
        }
      }
    eps[idx] = 1e-7f * ev;
    return;
  }
  int b = bid & 7, r = bid >> 3;       // XCD-affine
  int by = r >> 4, bx = r & 15;
  const unsigned short* Ab = fgT  + ((size_t)b * L + by * 64) * C_IN;
  const unsigned short* Bb = mbgT + ((size_t)b * L + bx * 64) * C_IN;
  int tid = threadIdx.x, lane = tid & 63, wv = tid >> 6;   // wv in [0,8)
  int row_off = lane >> 5, slot = lane & 31;
  int q = slot >> 3, sl = slot & 7;
  #pragma unroll
  for (int i = 0; i < 4; i++){
    int rr = wv * 8 + i * 2 + row_off;
    int srcs = q * 8 + (sl ^ (rr & 7));
    GLDS16(Ab + (size_t)rr * C_IN + srcs * 8, &As[wv * 8 + i * 2][0]);
    GLDS16(Bb + (size_t)rr * C_IN + srcs * 8, &Bs[wv * 8 + i * 2][0]);
  }
  __syncthreads();
  int wm = (wv & 1) * 32, wn = (wv >> 1) * 16;
  int rsel = lane & 15, sx = lane >> 4;
  f32x4 acc[2] = {};
  #pragma unroll
  for (int st = 0; st < 8; st++){
    int gs = st * 4 + sx, qq = gs >> 3, ss = gs & 7;
    short8 af[2], bf;
    #pragma unroll
    for (int i = 0; i < 2; i++){
      int ra = wm + i * 16 + rsel;
      af[i] = *(const short8*)&As[ra][(qq * 8 + (ss ^ (ra & 7))) * 8];
    }
    int rb = wn + rsel;
    bf = *(const short8*)&Bs[rb][(qq * 8 + (ss ^ (rb & 7))) * 8];
    #pragma unroll
    for (int i = 0; i < 2; i++)
      acc[i] = __builtin_amdgcn_mfma_f32_16x16x32_bf16(af[i], bf, acc[i], 0, 0, 0);
  }
  unsigned short* Db = D + ((size_t)b << 20);
  int rowb = (lane >> 4) * 4, col = lane & 15;
  #pragma unroll
  for (int i = 0; i < 2; i++)
    #pragma unroll
    for (int r2 = 0; r2 < 4; r2++)
      Db[(size_t)(by * 64 + wm + i * 16 + rowb + r2) * L + bx * 64 + wn + col] = f2bf(acc[i][r2]);
}

// ---------------- S2: W = 3x3 box of D, 2x2 q-tile per block --------------------
__global__ __launch_bounds__(256) void box3(const unsigned short* __restrict__ D,
                                            unsigned short* __restrict__ W){
  int bid = blockIdx.x;                // 2312 = 8 * 289: b = bid&7
  int b = bid & 7;
  int tile = bid >> 3;                 // 0..288 (17x17 tiles of 2x2 ext cells)
  int ty = tile / 17, tx = tile - ty * 17;
  int qy0 = ty * 2, qx0 = tx * 2;
  const unsigned short* Db = D + ((size_t)b << 20);
  int v0 = threadIdx.x * 4;
  uint2 src[4][4];
  #pragma unroll
  for (int ry = 0; ry < 4; ry++){
    int y = qy0 - 2 + ry;
    #pragma unroll
    for (int rx = 0; rx < 4; rx++){
      int x = qx0 - 2 + rx;
      uint2 v; v.x = 0u; v.y = 0u;
      if ((unsigned)y < HW && (unsigned)x < HW)
        v = *(const uint2*)(Db + ((size_t)(y * HW + x) << 10) + v0);
      src[ry][rx] = v;
    }
  }
  #pragma unroll
  for (int oy = 0; oy < 2; oy++)
    #pragma unroll
    for (int ox = 0; ox < 2; ox++){
      float a0 = 0.f, a1 = 0.f, a2 = 0.f, a3 = 0.f;
      #pragma unroll
      for (int dy = 0; dy < 3; dy++)
        #pragma unroll
        for (int dx = 0; dx < 3; dx++){
          uint2 v = src[oy + dy][ox + dx];
          a0 += __uint_as_float(v.x << 16);
          a1 += __uint_as_float(v.x & 0xffff0000u);
          a2 += __uint_as_float(v.y << 16);
          a3 += __uint_as_float(v.y & 0xffff0000u);
        }
      int q2 = (qy0 + oy) * 34 + (qx0 + ox);
      ushort4 o;
      o.x = f2bf(a0); o.y = f2bf(a1); o.z = f2bf(a2); o.w = f2bf(a3);
      *(ushort4*)(W + ((size_t)(b * NQ + q2) << 10) + v0) = o;
    }
}

// ------- vector tap read: 2 bf16 at idx..idx+1 from a 1024-elem LDS row ---------
static __device__ __forceinline__ unsigned tap2(const unsigned* __restrict__ row32,
                                                int idx, int sh){
  int a0 = idx & ~1;
  unsigned q0 = row32[a0 >> 1];
  if (sh == 0) return q0;
  unsigned q1 = row32[((a0 + 2) & 1023) >> 1];
  return (q0 >> 16) | (q1 << 16);
}

// ---------------- S3: 2x4 p-tile, 512 thr: diag 9-tap + softmax -> AR -----------
__global__ __launch_bounds__(512) void prop_softmax_diag(const unsigned short* __restrict__ W,
                                                         const float* __restrict__ eps,
                                                         const float* __restrict__ rn,
                                                         unsigned short* __restrict__ AR){
  __shared__ __align__(16) unsigned short Wl[24][1024];   // 48 KB
  __shared__ float redm[8][8], reds[8][8];
  int bid = blockIdx.x;                // 1024: b = bid&7
  int b = bid & 7, tile = bid >> 3;    // 128 tiles of 2(y)x4(x)
  int py0 = (tile >> 3) * 2, px0 = (tile & 7) * 4;
  const unsigned short* Wb = W + (size_t)b * NQ * L;
  int tid = threadIdx.x, lane = tid & 63, wv = tid >> 6;   // wv in [0,8)
  // stage 24 W rows: ext (py0+ry, px0+rx), ry 0..3, rx 0..5 (all valid ext coords)
  #pragma unroll
  for (int k = 0; k < 6; k++){
    int u = k * 8 + wv;                // 0..47 half-row units
    int rr = u >> 1, half = u & 1;
    int ry = rr / 6, rx = rr - ry * 6;
    int qs = (py0 + ry) * 34 + (px0 + rx);
    GLDS16(Wb + (((size_t)qs) << 10) + half * 512 + lane * 8, &Wl[rr][half * 512]);
  }
  int l0 = tid * 2;
  int ly = l0 >> 5, lx0 = l0 & 31;
  float2 rnl = *(const float2*)&rn[b * L + l0];
  float ev[8];
  #pragma unroll
  for (int o = 0; o < 8; o++)
    ev[o] = eps[b * L + (py0 + (o >> 2)) * HW + (px0 + (o & 3))];
  __syncthreads();
  float val[8][2];
  #pragma unroll
  for (int o = 0; o < 8; o++){
    int oy = o >> 2, ox = o & 3;
    float a0 = 0.f, a1 = 0.f;
    #pragma unroll
    for (int s = 0; s < 9; s++){
      const int dy = s / 3 - 1, dx = s % 3 - 1;
      const int dlt = dy * 32 + dx;
      const int sh = dx & 1;
      bool rok = (unsigned)(ly + dy) < HW;
      int idx = (l0 + dlt) & 1023;
      unsigned ov = tap2((const unsigned*)&Wl[(oy + dy + 1) * 6 + (ox + dx + 1)][0], idx, sh);
      float f0 = __uint_as_float(ov << 16), f1 = __uint_as_float(ov & 0xffff0000u);
      a0 += (rok && (unsigned)(lx0 + 0 + dx) < HW) ? f0 : 0.f;
      a1 += (rok && (unsigned)(lx0 + 1 + dx) < HW) ? f1 : 0.f;
    }
    val[o][0] = rnl.x * (a0 + ev[o]); val[o][1] = rnl.y * (a1 + ev[o]);
  }
  #pragma unroll
  for (int o = 0; o < 8; o++){
    float m = fmaxf(val[o][0], val[o][1]);
    #pragma unroll
    for (int off = 32; off; off >>= 1) m = fmaxf(m, __shfl_xor(m, off));
    if (lane == 0) redm[wv][o] = m;
  }
  __syncthreads();
  float mf[8];
  #pragma unroll
  for (int o = 0; o < 8; o++){
    float m = redm[0][o];
    #pragma unroll
    for (int w = 1; w < 8; w++) m = fmaxf(m, redm[w][o]);
    mf[o] = m;
  }
  float e[8][2];
  #pragma unroll
  for (int o = 0; o < 8; o++){
    e[o][0] = __expf(val[o][0] - mf[o]);
    e[o][1] = __expf(val[o][1] - mf[o]);
    float t = e[o][0] + e[o][1];
    #pragma unroll
    for (int off = 32; off; off >>= 1) t += __shfl_xor(t, off);
    if (lane == 0) reds[wv][o] = t;
  }
  __syncthreads();
  #pragma unroll
  for (int o = 0; o < 8; o++){
    float t = reds[0][o];
    #pragma unroll
    for (int w = 1; w < 8; w++) t += reds[w][o];
    float inv = 1.f / t;
    int p = (py0 + (o >> 2)) * HW + (px0 + (o & 3));
    unsigned short* O = AR + ((size_t)b << 20) + ((size_t)p << 10);
    ushort2 ov;
    ov.x = f2bf(e[o][0] * inv * rnl.x); ov.y = f2bf(e[o][1] * inv * rnl.y);
    *(ushort2*)&O[l0] = ov;
  }
}

// ---------------- S4: 2x4 p-tile, 512 thr: U = sum_s gated AR[p+ds][v+ds] -------
__global__ __launch_bounds__(512) void u_stencil(const unsigned short* __restrict__ AR,
                                                 unsigned short* __restrict__ U){
  __shared__ __align__(16) unsigned short Al[24][1024];   // 48 KB
  int bid = blockIdx.x;                // 1024: b = bid&7
  int b = bid & 7, tile = bid >> 3;
  int py0 = (tile >> 3) * 2, px0 = (tile & 7) * 4;
  int tid = threadIdx.x, lane = tid & 63, wv = tid >> 6;
  const unsigned short* A = AR + ((size_t)b << 20);
  // stage 24 AR rows: p' = (py0+ry-1, px0+rx-1); OOB rows staged from 0, masked
  #pragma unroll
  for (int k = 0; k < 6; k++){
    int u = k * 8 + wv;
    int rr = u >> 1, half = u & 1;
    int ry = rr / 6, rx = rr - ry * 6;
    int yy = py0 + ry - 1, xx = px0 + rx - 1;
    bool rok = ((unsigned)yy < HW) && ((unsigned)xx < HW);
    int p2 = rok ? (yy * HW + xx) : 0;
    GLDS16(A + (((size_t)p2) << 10) + half * 512 + lane * 8, &Al[rr][half * 512]);
  }
  int vmask = 0;
  #pragma unroll
  for (int rr = 0; rr < 24; rr++){
    int ry = rr / 6, rx = rr - ry * 6;
    int yy = py0 + ry - 1, xx = px0 + rx - 1;
    if (((unsigned)yy < HW) && ((unsigned)xx < HW)) vmask |= 1 << rr;
  }
  __syncthreads();
  int v0 = tid * 2;
  int vy = v0 >> 5, vx0 = v0 & 31;
  #pragma unroll
  for (int o = 0; o < 8; o++){
    int oy = o >> 2, ox = o & 3;
    float a0 = 0.f, a1 = 0.f;
    #pragma unroll
    for (int s = 0; s < 9; s++){
      const int dy = s / 3 - 1, dx = s % 3 - 1;
      const int dlt = dy * 32 + dx;
      const int sh = dx & 1;
      const int rr = (oy + dy + 1) * 6 + (ox + dx + 1);
      bool rok = ((vmask >> rr) & 1) && ((unsigned)(vy + dy) < HW);
      int idx = (v0 + dlt) & 1023;
      unsigned ov = tap2((const unsigned*)&Al[rr][0], idx, sh);
      float f0 = __uint_as_float(ov << 16), f1 = __uint_as_float(ov & 0xffff0000u);
      a0 += (rok && (unsigned)(vx0 + 0 + dx) < HW) ? f0 : 0.f;
      a1 += (rok && (unsigned)(vx0 + 1 + dx) < HW) ? f1 : 0.f;
    }
    int p = (py0 + oy) * HW + (px0 + ox);
    unsigned short* O = U + ((size_t)b << 20) + ((size_t)p << 10);
    ushort2 ov2;
    ov2.x = f2bf(a0); ov2.y = f2bf(a1);
    *(ushort2*)&O[v0] = ov2;
  }
}

// ---------------- G2: finalT = mask? (U.mbgS)/9 : fgT  (2-chunk staging) --------
__global__ __launch_bounds__(512) void gemm3_final(const unsigned short* __restrict__ U,
                                                   const unsigned short* __restrict__ mbgS,
                                                   const float* __restrict__ mask,
                                                   const unsigned short* __restrict__ fgT,
                                                   unsigned short* __restrict__ finalT){
  __shared__ unsigned short As[4][64][64];   // 32 KB
  __shared__ unsigned short Bs[4][64][64];   // 32 KB
  int bid = blockIdx.x;                // 512: b = bid&7
  int b = bid & 7, r = bid >> 3;       // r in [0,64)
  int mt = r >> 2, ct = r & 3;
  int tid = threadIdx.x, lane = tid & 63, wv = tid >> 6;   // wv in [0,8)
  int wm = (wv & 1) * 32, wn = (wv >> 1) * 16;
  int rsel = lane & 15;
  int srow = lane >> 3, scol = ((lane & 7) ^ srow) * 8;
  const unsigned short* Ag = U    + ((size_t)b * L + mt * 64 + wv * 8 + srow) * L + scol;
  const unsigned short* Bg = mbgS + ((size_t)b * C_IN + ct * 64 + wv * 8 + srow) * L + scol;
  GLDS16(Ag,      &As[0][wv * 8][0]);
  GLDS16(Bg,      &Bs[0][wv * 8][0]);
  GLDS16(Ag + 64, &As[1][wv * 8][0]);
  GLDS16(Bg + 64, &Bs[1][wv * 8][0]);
  __syncthreads();
  f32x4 acc[2] = {};
  int cur = 0;
  for (int t2 = 0; t2 < 8; ++t2){      // 2 K-chunks of 64 per iteration
    short8 af[2][2][2], bf[2][2];      // [half][kk][i] / [half][kk]
    #pragma unroll
    for (int half = 0; half < 2; half++)
      #pragma unroll
      for (int kk = 0; kk < 2; kk++){
        int s0 = kk * 4 + (lane >> 4);
        int col = ((s0 ^ (rsel & 7)) << 3);
        #pragma unroll
        for (int i = 0; i < 2; i++)
          af[half][kk][i] = *(const short8*)&As[cur + half][wm + i * 16 + rsel][col];
        bf[half][kk] = *(const short8*)&Bs[cur + half][wn + rsel][col];
      }
    if (t2 + 1 < 8){
      int nb = cur ^ 2;
      size_t kt = (size_t)(2 * t2 + 2) * 64;
      GLDS16(Ag + kt,      &As[nb][wv * 8][0]);
      GLDS16(Bg + kt,      &Bs[nb][wv * 8][0]);
      GLDS16(Ag + kt + 64, &As[nb + 1][wv * 8][0]);
      GLDS16(Bg + kt + 64, &Bs[nb + 1][wv * 8][0]);
    }
    #pragma unroll
    for (int half = 0; half < 2; half++)
      #pragma unroll
      for (int kk = 0; kk < 2; kk++)
        #pragma unroll
        for (int i = 0; i < 2; i++)
          acc[i] = __builtin_amdgcn_mfma_f32_16x16x32_bf16(af[half][kk][i], bf[half][kk], acc[i], 0, 0, 0);
    __syncthreads();
    cur ^= 2;
  }
  int rowb = (lane >> 4) * 4, col = lane & 15;
  #pragma unroll
  for (int i = 0; i < 2; i++)
    #pragma unroll
    for (int r2 = 0; r2 < 4; r2++){
      int p = mt * 64 + wm + i * 16 + rowb + r2;
      int c = ct * 64 + wn + col;
      unsigned short o;
      if (mask[p] != 0.f) o = f2bf(acc[i][r2] * (1.f / 9.f));
      else                o = fgT[((size_t)b * L + p) * C_IN + c];
      finalT[((size_t)b * L + p) * C_IN + c] = o;
    }
}

// ---------------- K4: branch convs, 2-tap-per-barrier staging -------------------
__global__ __launch_bounds__(512) void branch_gemm(const unsigned short* __restrict__ finalT,
                                                   const unsigned short* __restrict__ Wr,
                                                   const float* __restrict__ conv_b,
                                                   const unsigned short* __restrict__ zpage,
                                                   float* __restrict__ out){
  __shared__ unsigned short As[4][64][64];   // 32 KB
  __shared__ unsigned short Bs[4][64][64];   // 32 KB
  int nwg = gridDim.x, bid = blockIdx.x;     // 512
  int nid = (bid & 7) * (nwg >> 3) + (bid >> 3);   // XCD-affine
  int bg = nid >> 4, pt = nid & 15;
  int b = bg >> 2, g = bg & 3;
  int rate = 1 << g;
  int p0 = pt * 64;
  int tid = threadIdx.x, lane = tid & 63, wv = tid >> 6;   // wv in [0,8)
  int wm = (wv & 1) * 32, wn = (wv >> 1) * 16;
  int rsel = lane & 15;
  int srow = lane >> 3;
  int scol = ((lane & 7) ^ srow) * 8;
  const unsigned short* FT = finalT + (size_t)b * L * C_IN;
  const unsigned short* WG = Wr + (size_t)(g * 9) * 64 * C_IN;

  int prow = p0 + wv * 8 + srow;
  int ayy = prow >> 5, axx = prow & 31;
  auto a_src = [&](int t) -> const unsigned short* {
    int s = t >> 2, q = t & 3;
    int dy = s / 3 - 1, dx = s - (s / 3) * 3 - 1;
    int iy = ayy + rate * dy, ix = axx + rate * dx;
    if ((unsigned)iy < HW && (unsigned)ix < HW)
      return FT + (size_t)(iy * HW + ix) * C_IN + q * 64 + scol;
    return zpage;
  };
  auto b_src = [&](int t) -> const unsigned short* {
    int s = t >> 2, q = t & 3;
    int n = wv * 8 + srow;
    return WG + (size_t)(s * 64 + n) * C_IN + q * 64 + scol;
  };

  f32x4 acc[2] = {};
  GLDS16(a_src(0), &As[0][wv * 8][0]);
  GLDS16(b_src(0), &Bs[0][wv * 8][0]);
  GLDS16(a_src(1), &As[1][wv * 8][0]);
  GLDS16(b_src(1), &Bs[1][wv * 8][0]);
  __syncthreads();
  int cur = 0;
  for (int t2 = 0; t2 < 18; ++t2){     // 2 taps per iteration (36 total)
    short8 af[2][2][2], bf[2][2];
    #pragma unroll
    for (int half = 0; half < 2; half++)
      #pragma unroll
      for (int kk = 0; kk < 2; kk++){
        int s0 = kk * 4 + (lane >> 4);
        int col = ((s0 ^ (rsel & 7)) << 3);
        #pragma unroll
        for (int i = 0; i < 2; i++)
          af[half][kk][i] = *(const short8*)&As[cur + half][wm + i * 16 + rsel][col];
        bf[half][kk] = *(const short8*)&Bs[cur + half][wn + rsel][col];
      }
    if (t2 + 1 < 18){
      int nb = cur ^ 2;
      GLDS16(a_src(2 * t2 + 2), &As[nb][wv * 8][0]);
      GLDS16(b_src(2 * t2 + 2), &Bs[nb][wv * 8][0]);
      GLDS16(a_src(2 * t2 + 3), &As[nb + 1][wv * 8][0]);
      GLDS16(b_src(2 * t2 + 3), &Bs[nb + 1][wv * 8][0]);
    }
    #pragma unroll
    for (int half = 0; half < 2; half++)
      #pragma unroll
      for (int kk = 0; kk < 2; kk++)
        #pragma unroll
        for (int i = 0; i < 2; i++)
          acc[i] = __builtin_amdgcn_mfma_f32_16x16x32_bf16(af[half][kk][i], bf[half][kk], acc[i], 0, 0, 0);
    __syncthreads();
    cur ^= 2;
  }
  int rowb = (lane >> 4) * 4, col = lane & 15;
  float* O = out + (size_t)(b * 256 + g * 64) * L;
  int n = wn + col;
  float bias = conv_b[g * 64 + n];
  #pragma unroll
  for (int i = 0; i < 2; i++)
    #pragma unroll
    for (int r2 = 0; r2 < 4; r2++){
      int p = p0 + wm + i * 16 + rowb + r2;
      O[(size_t)n * L + p] = fmaxf(acc[i][r2] + bias, 0.f);
    }
}

// ---------------- workspace layout (bytes) — round-12 layout --------------------
// [0,        16777216) : D    (8*1024*1024 bf16)
// [16777216, 35717120) : W    (8*1156*1024 bf16)
// [35717120, 52494336) : AR   (8*1024*1024 bf16)
// [52494336, 69271552) : U    (8*1024*1024 bf16)
// [69271552, 73465856) : mbgT
// [73465856, 77660160) : mbgS
// [77660160, 81854464) : finalT
// [81854464, 83034112) : Wr
// [83034112, 83427328) : psum (written unconditionally — no init)
// [83427328, 83460096) : rn
// [83460096, 83492864) : eps
// [83492864, 83493376) : zpage
// fgT lives in d_out[0 .. 4.2MB)

extern "C" void kernel_launch(void* const* d_in, const int* in_sizes, int n_in,
                              void* d_out, int out_size, void* d_ws, size_t ws_size,
                              hipStream_t stream){
  const float* fg     = (const float*)d_in[0];
  const float* mask   = (const float*)d_in[1];
  const float* bgd    = (const float*)d_in[2];
  const float* conv_w = (const float*)d_in[3];
  const float* conv_b = (const float*)d_in[4];

  char* ws = (char*)d_ws;
  unsigned short* D      = (unsigned short*)(ws + 0);
  unsigned short* W      = (unsigned short*)(ws + 16777216);
  unsigned short* AR     = (unsigned short*)(ws + 35717120);
  unsigned short* U      = (unsigned short*)(ws + 52494336);
  unsigned short* mbgT   = (unsigned short*)(ws + 69271552);
  unsigned short* mbgS   = (unsigned short*)(ws + 73465856);
  unsigned short* finalT = (unsigned short*)(ws + 77660160);
  unsigned short* Wr     = (unsigned short*)(ws + 81854464);
  float*          psum   = (float*)(ws + 83034112);
  float*          rn     = (float*)(ws + 83427328);
  float*          eps    = (float*)(ws + 83460096);
  unsigned short* zpage  = (unsigned short*)(ws + 83492864);
  unsigned short* fgT    = (unsigned short*)d_out;
  float* out = (float*)d_out;

  fused_prep<<<2816, 256, 0, stream>>>(fg, bgd, mask, fgT, mbgT, mbgS, psum,
                                       conv_w, Wr, zpage);
  gemm_d_rn<<<2064, 512, 0, stream>>>(fgT, mbgT, D, psum, rn, eps);
  box3<<<2312, 256, 0, stream>>>(D, W);
  prop_softmax_diag<<<1024, 512, 0, stream>>>(W, eps, rn, AR);
  u_stencil<<<1024, 512, 0, stream>>>(AR, U);
  gemm3_final<<<512, 512, 0, stream>>>(U, mbgS, mask, fgT, finalT);
  branch_gemm<<<512, 512, 0, stream>>>(finalT, Wr, conv_b, zpage, out);
}

// Round 17
// 98.359 us; speedup vs baseline: 1.0437x; 1.0437x over previous
//
#include <hip/hip_runtime.h>

typedef __attribute__((ext_vector_type(8))) short short8;
typedef __attribute__((ext_vector_type(4))) float f32x4;
typedef __attribute__((ext_vector_type(4))) unsigned int uint4v;

#define HW 32
#define L 1024        // HW*HW
#define C_IN 256
#define BATCH 8
#define NQ 1156       // 34*34 extended grid

static __device__ __forceinline__ unsigned short f2bf(float f){
  unsigned int u = __float_as_uint(f);
  unsigned int r = (u + 0x7FFFu + ((u >> 16) & 1u)) >> 16;   // RNE (no NaN inputs)
  return (unsigned short)r;
}
static __device__ __forceinline__ float bf2f(unsigned short h){
  return __uint_as_float(((unsigned int)h) << 16);
}

#define GLDS16(g, l) __builtin_amdgcn_global_load_lds(                          \
    (const __attribute__((address_space(1))) void*)(g),                         \
    (__attribute__((address_space(3))) void*)(l), 16, 0, 0)

// ---------------- D1: vectorized transposes + moment partials + Wr prep ---------
__global__ __launch_bounds__(256) void fused_prep(const float* __restrict__ fg,
                                                  const float* __restrict__ bgd,
                                                  const float* __restrict__ mask,
                                                  unsigned short* __restrict__ fgT,
                                                  unsigned short* __restrict__ mbgT,
                                                  unsigned short* __restrict__ mbgS,
                                                  float* __restrict__ psum,
                                                  const float* __restrict__ conv_w,
                                                  unsigned short* __restrict__ Wr,
                                                  unsigned short* __restrict__ zpage){
  __shared__ float T[64][65];
  int blk = blockIdx.x;
  if (blk >= 512){
    if (blk == 512) zpage[threadIdx.x] = 0;    // 512 B zero page
    int idx = (blk - 512) * 256 + threadIdx.x; // 589824 Wr elements
    int c = idx & 255;
    int rest = idx >> 8;
    int n = rest & 63;
    int sg = rest >> 6;
    int s = sg % 9, g = sg / 9;
    Wr[idx] = f2bf(conv_w[(((size_t)(g * 64 + n)) * C_IN + c) * 9 + s]);
    return;
  }
  const int NP = BATCH * L;
  int bx = blk & 15, cb = (blk >> 4) & 3, b = blk >> 6;
  int p0 = bx * 64, c0 = cb * 64;
  int tid = threadIdx.x;
  int rr = tid >> 4, px = (tid & 15) * 4;      // read-phase coords
  int cx = tid & 15, ppb = tid >> 4;           // write-phase coords
  const float* F = fg  + ((size_t)b * C_IN + c0) * L + p0;
  const float* G = bgd + ((size_t)b * C_IN + c0) * L + p0;

  #pragma unroll
  for (int it = 0; it < 4; it++){
    int cc = it * 16 + rr;
    float4 v = *(const float4*)(F + (size_t)cc * L + px);
    T[cc][px] = v.x; T[cc][px + 1] = v.y; T[cc][px + 2] = v.z; T[cc][px + 3] = v.w;
  }
  __syncthreads();
  #pragma unroll
  for (int it = 0; it < 4; it++){
    int pp = it * 16 + ppb;
    float t0 = T[cx * 4][pp], t1 = T[cx * 4 + 1][pp], t2 = T[cx * 4 + 2][pp], t3 = T[cx * 4 + 3][pp];
    ushort4 o; o.x = f2bf(t0); o.y = f2bf(t1); o.z = f2bf(t2); o.w = f2bf(t3);
    *(ushort4*)&fgT[(size_t)(b * L + p0 + pp) * C_IN + c0 + cx * 4] = o;
    float s = t0 + t1 + t2 + t3;
    #pragma unroll
    for (int off = 8; off; off >>= 1) s += __shfl_xor(s, off, 16);
    if (cx == 0) psum[(size_t)(cb * 3 + 0) * NP + b * L + p0 + pp] = s;
  }
  __syncthreads();

  float4 mv = *(const float4*)(mask + p0 + px);
  mv.x = 1.f - mv.x; mv.y = 1.f - mv.y; mv.z = 1.f - mv.z; mv.w = 1.f - mv.w;
  #pragma unroll
  for (int it = 0; it < 4; it++){
    int cc = it * 16 + rr;
    float4 v = *(const float4*)(G + (size_t)cc * L + px);
    v.x *= mv.x; v.y *= mv.y; v.z *= mv.z; v.w *= mv.w;
    T[cc][px] = v.x; T[cc][px + 1] = v.y; T[cc][px + 2] = v.z; T[cc][px + 3] = v.w;
    ushort4 o; o.x = f2bf(v.x); o.y = f2bf(v.y); o.z = f2bf(v.z); o.w = f2bf(v.w);
    *(ushort4*)&mbgS[((size_t)b * C_IN + c0 + cc) * L + p0 + px] = o;
  }
  __syncthreads();
  #pragma unroll
  for (int it = 0; it < 4; it++){
    int pp = it * 16 + ppb;
    float t0 = T[cx * 4][pp], t1 = T[cx * 4 + 1][pp], t2 = T[cx * 4 + 2][pp], t3 = T[cx * 4 + 3][pp];
    ushort4 o; o.x = f2bf(t0); o.y = f2bf(t1); o.z = f2bf(t2); o.w = f2bf(t3);
    *(ushort4*)&mbgT[(size_t)(b * L + p0 + pp) * C_IN + c0 + cx * 4] = o;
    float s1 = t0 + t1 + t2 + t3;
    float s2 = t0 * t0 + t1 * t1 + t2 * t2 + t3 * t3;
    #pragma unroll
    for (int off = 8; off; off >>= 1){
      s1 += __shfl_xor(s1, off, 16);
      s2 += __shfl_xor(s2, off, 16);
    }
    if (cx == 0){
      psum[(size_t)(cb * 3 + 1) * NP + b * L + p0 + pp] = s1;
      psum[(size_t)(cb * 3 + 2) * NP + b * L + p0 + pp] = s2;
    }
  }
}

// ---------------- D2: gemm_d (512 thr, 8 waves) + rn/eps tail blocks ------------
__global__ __launch_bounds__(512) void gemm_d_rn(const unsigned short* __restrict__ fgT,
                                                 const unsigned short* __restrict__ mbgT,
                                                 unsigned short* __restrict__ D,
                                                 const float* __restrict__ psum,
                                                 float* __restrict__ rn,
                                                 float* __restrict__ eps){
  __shared__ unsigned short As[64][256];   // 32 KB
  __shared__ unsigned short Bs[64][256];   // 32 KB
  int bid = blockIdx.x;
  if (bid >= 2048){
    int idx = (bid - 2048) * 512 + threadIdx.x;  // 8192 over 16 blocks
    int b = idx >> 10, l = idx & 1023;
    int ly = l >> 5, lx = l & 31;
    const int NP = BATCH * L;
    float n2 = 2.304e-11f;                       // 2304 * 1e-14
    #pragma unroll
    for (int s = 0; s < 9; s++){
      int y = ly + s / 3 - 1, x = lx + s % 3 - 1;
      if ((unsigned)y < HW && (unsigned)x < HW){
        int q = b * L + y * HW + x;
        float s1 = 0.f, s2 = 0.f;
        #pragma unroll
        for (int k = 0; k < 4; k++){
          s1 += psum[(size_t)(k * 3 + 1) * NP + q];
          s2 += psum[(size_t)(k * 3 + 2) * NP + q];
        }
        n2 += s2 + 2e-7f * s1;
      }
    }
    rn[idx] = 1.f / sqrtf(n2);
    float ev = 0.f;
    const int tw[5] = {1, 2, 3, 2, 1};
    #pragma unroll
    for (int oy = -2; oy <= 2; oy++)
      #pragma unroll
      for (int ox = -2; ox <= 2; ox++){
        int y = ly + oy, x = lx + ox;
        if ((unsigned)y < HW && (unsigned)x < HW){
          int q = b * L + y * HW + x;
          float s0 = 0.f;
          #pragma unroll
          for (int k = 0; k < 4; k++) s0 += psum[(size_t)(k * 3 + 0) * NP + q];
          ev += (float)(tw[oy + 2] * tw[ox + 2]) * s0;
        }
      }
    eps[idx] = 1e-7f * ev;
    return;
  }
  int b = bid & 7, r = bid >> 3;       // XCD-affine
  int by = r >> 4, bx = r & 15;
  const unsigned short* Ab = fgT  + ((size_t)b * L + by * 64) * C_IN;
  const unsigned short* Bb = mbgT + ((size_t)b * L + bx * 64) * C_IN;
  int tid = threadIdx.x, lane = tid & 63, wv = tid >> 6;   // wv in [0,8)
  int row_off = lane >> 5, slot = lane & 31;
  int q = slot >> 3, sl = slot & 7;
  #pragma unroll
  for (int i = 0; i < 4; i++){
    int rr = wv * 8 + i * 2 + row_off;
    int srcs = q * 8 + (sl ^ (rr & 7));
    GLDS16(Ab + (size_t)rr * C_IN + srcs * 8, &As[wv * 8 + i * 2][0]);
    GLDS16(Bb + (size_t)rr * C_IN + srcs * 8, &Bs[wv * 8 + i * 2][0]);
  }
  __syncthreads();
  int wm = (wv & 1) * 32, wn = (wv >> 1) * 16;
  int rsel = lane & 15, sx = lane >> 4;
  f32x4 acc[2] = {};
  #pragma unroll
  for (int st = 0; st < 8; st++){
    int gs = st * 4 + sx, qq = gs >> 3, ss = gs & 7;
    short8 af[2], bf;
    #pragma unroll
    for (int i = 0; i < 2; i++){
      int ra = wm + i * 16 + rsel;
      af[i] = *(const short8*)&As[ra][(qq * 8 + (ss ^ (ra & 7))) * 8];
    }
    int rb = wn + rsel;
    bf = *(const short8*)&Bs[rb][(qq * 8 + (ss ^ (rb & 7))) * 8];
    #pragma unroll
    for (int i = 0; i < 2; i++)
      acc[i] = __builtin_amdgcn_mfma_f32_16x16x32_bf16(af[i], bf, acc[i], 0, 0, 0);
  }
  unsigned short* Db = D + ((size_t)b << 20);
  int rowb = (lane >> 4) * 4, col = lane & 15;
  #pragma unroll
  for (int i = 0; i < 2; i++)
    #pragma unroll
    for (int r2 = 0; r2 < 4; r2++)
      Db[(size_t)(by * 64 + wm + i * 16 + rowb + r2) * L + bx * 64 + wn + col] = f2bf(acc[i][r2]);
}

// ---------------- S2: W = 3x3 box of D, 2x2 q-tile per block --------------------
__global__ __launch_bounds__(256) void box3(const unsigned short* __restrict__ D,
                                            unsigned short* __restrict__ W){
  int bid = blockIdx.x;                // 2312 = 8 * 289: b = bid&7
  int b = bid & 7;
  int tile = bid >> 3;                 // 0..288 (17x17 tiles of 2x2 ext cells)
  int ty = tile / 17, tx = tile - ty * 17;
  int qy0 = ty * 2, qx0 = tx * 2;
  const unsigned short* Db = D + ((size_t)b << 20);
  int v0 = threadIdx.x * 4;
  uint2 src[4][4];
  #pragma unroll
  for (int ry = 0; ry < 4; ry++){
    int y = qy0 - 2 + ry;
    #pragma unroll
    for (int rx = 0; rx < 4; rx++){
      int x = qx0 - 2 + rx;
      uint2 v; v.x = 0u; v.y = 0u;
      if ((unsigned)y < HW && (unsigned)x < HW)
        v = *(const uint2*)(Db + ((size_t)(y * HW + x) << 10) + v0);
      src[ry][rx] = v;
    }
  }
  #pragma unroll
  for (int oy = 0; oy < 2; oy++)
    #pragma unroll
    for (int ox = 0; ox < 2; ox++){
      float a0 = 0.f, a1 = 0.f, a2 = 0.f, a3 = 0.f;
      #pragma unroll
      for (int dy = 0; dy < 3; dy++)
        #pragma unroll
        for (int dx = 0; dx < 3; dx++){
          uint2 v = src[oy + dy][ox + dx];
          a0 += __uint_as_float(v.x << 16);
          a1 += __uint_as_float(v.x & 0xffff0000u);
          a2 += __uint_as_float(v.y << 16);
          a3 += __uint_as_float(v.y & 0xffff0000u);
        }
      int q2 = (qy0 + oy) * 34 + (qx0 + ox);
      ushort4 o;
      o.x = f2bf(a0); o.y = f2bf(a1); o.z = f2bf(a2); o.w = f2bf(a3);
      *(ushort4*)(W + ((size_t)(b * NQ + q2) << 10) + v0) = o;
    }
}

// ------- vector tap read: 2 bf16 at idx..idx+1 from a 1024-elem LDS row ---------
static __device__ __forceinline__ unsigned tap2(const unsigned* __restrict__ row32,
                                                int idx, int sh){
  int a0 = idx & ~1;
  unsigned q0 = row32[a0 >> 1];
  if (sh == 0) return q0;
  unsigned q1 = row32[((a0 + 2) & 1023) >> 1];
  return (q0 >> 16) | (q1 << 16);
}

// ---------------- S3: 2x2 p-tile, 512 thr: diag 9-tap + softmax -> AR -----------
__global__ __launch_bounds__(512) void prop_softmax_diag(const unsigned short* __restrict__ W,
                                                         const float* __restrict__ eps,
                                                         const float* __restrict__ rn,
                                                         unsigned short* __restrict__ AR){
  __shared__ __align__(16) unsigned short Wl[16][1024];   // 32 KB
  __shared__ float redm[8][4], reds[8][4];
  int bid = blockIdx.x;                // 2048: b = bid&7
  int b = bid & 7, tile = bid >> 3;    // 256 tiles of 2x2
  int py0 = (tile >> 4) * 2, px0 = (tile & 15) * 2;
  const unsigned short* Wb = W + (size_t)b * NQ * L;
  int tid = threadIdx.x, lane = tid & 63, wv = tid >> 6;   // wv in [0,8)
  #pragma unroll
  for (int k = 0; k < 4; k++){
    int u = k * 8 + wv;                // 0..31 half-row units
    int rr = u >> 1, half = u & 1;
    int qs = (py0 + (rr >> 2)) * 34 + (px0 + (rr & 3));
    GLDS16(Wb + (((size_t)qs) << 10) + half * 512 + lane * 8, &Wl[rr][half * 512]);
  }
  int l0 = tid * 2;
  int ly = l0 >> 5, lx0 = l0 & 31;
  float2 rnl = *(const float2*)&rn[b * L + l0];
  float ev[4];
  #pragma unroll
  for (int o = 0; o < 4; o++)
    ev[o] = eps[b * L + (py0 + (o >> 1)) * HW + (px0 + (o & 1))];
  __syncthreads();
  float val[4][2];
  #pragma unroll
  for (int o = 0; o < 4; o++){
    int oy = o >> 1, ox = o & 1;
    float a0 = 0.f, a1 = 0.f;
    #pragma unroll
    for (int s = 0; s < 9; s++){
      const int dy = s / 3 - 1, dx = s % 3 - 1;
      const int dlt = dy * 32 + dx;
      const int sh = dx & 1;
      bool rok = (unsigned)(ly + dy) < HW;
      int idx = (l0 + dlt) & 1023;
      unsigned ov = tap2((const unsigned*)&Wl[(oy + dy + 1) * 4 + (ox + dx + 1)][0], idx, sh);
      float f0 = __uint_as_float(ov << 16), f1 = __uint_as_float(ov & 0xffff0000u);
      a0 += (rok && (unsigned)(lx0 + 0 + dx) < HW) ? f0 : 0.f;
      a1 += (rok && (unsigned)(lx0 + 1 + dx) < HW) ? f1 : 0.f;
    }
    val[o][0] = rnl.x * (a0 + ev[o]); val[o][1] = rnl.y * (a1 + ev[o]);
  }
  #pragma unroll
  for (int o = 0; o < 4; o++){
    float m = fmaxf(val[o][0], val[o][1]);
    #pragma unroll
    for (int off = 32; off; off >>= 1) m = fmaxf(m, __shfl_xor(m, off));
    if (lane == 0) redm[wv][o] = m;
  }
  __syncthreads();
  float mf[4];
  #pragma unroll
  for (int o = 0; o < 4; o++){
    float m = redm[0][o];
    #pragma unroll
    for (int w = 1; w < 8; w++) m = fmaxf(m, redm[w][o]);
    mf[o] = m;
  }
  float e[4][2];
  #pragma unroll
  for (int o = 0; o < 4; o++){
    e[o][0] = __expf(val[o][0] - mf[o]);
    e[o][1] = __expf(val[o][1] - mf[o]);
    float t = e[o][0] + e[o][1];
    #pragma unroll
    for (int off = 32; off; off >>= 1) t += __shfl_xor(t, off);
    if (lane == 0) reds[wv][o] = t;
  }
  __syncthreads();
  #pragma unroll
  for (int o = 0; o < 4; o++){
    float t = reds[0][o];
    #pragma unroll
    for (int w = 1; w < 8; w++) t += reds[w][o];
    float inv = 1.f / t;
    int p = (py0 + (o >> 1)) * HW + (px0 + (o & 1));
    unsigned short* O = AR + ((size_t)b << 20) + ((size_t)p << 10);
    ushort2 ov;
    ov.x = f2bf(e[o][0] * inv * rnl.x); ov.y = f2bf(e[o][1] * inv * rnl.y);
    *(ushort2*)&O[l0] = ov;
  }
}

// ---------------- S4: 2x2 p-tile, 512 thr: U = sum_s gated AR[p+ds][v+ds] -------
__global__ __launch_bounds__(512) void u_stencil(const unsigned short* __restrict__ AR,
                                                 unsigned short* __restrict__ U){
  __shared__ __align__(16) unsigned short Al[16][1024];   // 32 KB
  int bid = blockIdx.x;                // 2048: b = bid&7
  int b = bid & 7, tile = bid >> 3;
  int py0 = (tile >> 4) * 2, px0 = (tile & 15) * 2;
  int tid = threadIdx.x, lane = tid & 63, wv = tid >> 6;
  const unsigned short* A = AR + ((size_t)b << 20);
  #pragma unroll
  for (int k = 0; k < 4; k++){
    int u = k * 8 + wv;
    int rr = u >> 1, half = u & 1;
    int yy = py0 + (rr >> 2) - 1, xx = px0 + (rr & 3) - 1;
    bool rok = ((unsigned)yy < HW) && ((unsigned)xx < HW);
    int p2 = rok ? (yy * HW + xx) : 0;
    GLDS16(A + (((size_t)p2) << 10) + half * 512 + lane * 8, &Al[rr][half * 512]);
  }
  int vmask = 0;
  #pragma unroll
  for (int rr = 0; rr < 16; rr++){
    int yy = py0 + (rr >> 2) - 1, xx = px0 + (rr & 3) - 1;
    if (((unsigned)yy < HW) && ((unsigned)xx < HW)) vmask |= 1 << rr;
  }
  __syncthreads();
  int v0 = tid * 2;
  int vy = v0 >> 5, vx0 = v0 & 31;
  #pragma unroll
  for (int o = 0; o < 4; o++){
    int oy = o >> 1, ox = o & 1;
    float a0 = 0.f, a1 = 0.f;
    #pragma unroll
    for (int s = 0; s < 9; s++){
      const int dy = s / 3 - 1, dx = s % 3 - 1;
      const int dlt = dy * 32 + dx;
      const int sh = dx & 1;
      const int rr = (oy + dy + 1) * 4 + (ox + dx + 1);
      bool rok = ((vmask >> rr) & 1) && ((unsigned)(vy + dy) < HW);
      int idx = (v0 + dlt) & 1023;
      unsigned ov = tap2((const unsigned*)&Al[rr][0], idx, sh);
      float f0 = __uint_as_float(ov << 16), f1 = __uint_as_float(ov & 0xffff0000u);
      a0 += (rok && (unsigned)(vx0 + 0 + dx) < HW) ? f0 : 0.f;
      a1 += (rok && (unsigned)(vx0 + 1 + dx) < HW) ? f1 : 0.f;
    }
    int p = (py0 + oy) * HW + (px0 + ox);
    unsigned short* O = U + ((size_t)b << 20) + ((size_t)p << 10);
    ushort2 ov2;
    ov2.x = f2bf(a0); ov2.y = f2bf(a1);
    *(ushort2*)&O[v0] = ov2;
  }
}

// ---------------- G2: finalT = mask? (U.mbgS)/9 : fgT  (2-chunk staging) --------
__global__ __launch_bounds__(512) void gemm3_final(const unsigned short* __restrict__ U,
                                                   const unsigned short* __restrict__ mbgS,
                                                   const float* __restrict__ mask,
                                                   const unsigned short* __restrict__ fgT,
                                                   unsigned short* __restrict__ finalT){
  __shared__ unsigned short As[4][64][64];   // 32 KB
  __shared__ unsigned short Bs[4][64][64];   // 32 KB
  int bid = blockIdx.x;                // 512: b = bid&7
  int b = bid & 7, r = bid >> 3;       // r in [0,64)
  int mt = r >> 2, ct = r & 3;
  int tid = threadIdx.x, lane = tid & 63, wv = tid >> 6;   // wv in [0,8)
  int wm = (wv & 1) * 32, wn = (wv >> 1) * 16;
  int rsel = lane & 15;
  int srow = lane >> 3, scol = ((lane & 7) ^ srow) * 8;
  const unsigned short* Ag = U    + ((size_t)b * L + mt * 64 + wv * 8 + srow) * L + scol;
  const unsigned short* Bg = mbgS + ((size_t)b * C_IN + ct * 64 + wv * 8 + srow) * L + scol;
  GLDS16(Ag,      &As[0][wv * 8][0]);
  GLDS16(Bg,      &Bs[0][wv * 8][0]);
  GLDS16(Ag + 64, &As[1][wv * 8][0]);
  GLDS16(Bg + 64, &Bs[1][wv * 8][0]);
  __syncthreads();
  f32x4 acc[2] = {};
  int cur = 0;
  for (int t2 = 0; t2 < 8; ++t2){      // 2 K-chunks of 64 per iteration
    short8 af[2][2][2], bf[2][2];      // [half][kk][i] / [half][kk]
    #pragma unroll
    for (int half = 0; half < 2; half++)
      #pragma unroll
      for (int kk = 0; kk < 2; kk++){
        int s0 = kk * 4 + (lane >> 4);
        int col = ((s0 ^ (rsel & 7)) << 3);
        #pragma unroll
        for (int i = 0; i < 2; i++)
          af[half][kk][i] = *(const short8*)&As[cur + half][wm + i * 16 + rsel][col];
        bf[half][kk] = *(const short8*)&Bs[cur + half][wn + rsel][col];
      }
    if (t2 + 1 < 8){
      int nb = cur ^ 2;
      size_t kt = (size_t)(2 * t2 + 2) * 64;
      GLDS16(Ag + kt,      &As[nb][wv * 8][0]);
      GLDS16(Bg + kt,      &Bs[nb][wv * 8][0]);
      GLDS16(Ag + kt + 64, &As[nb + 1][wv * 8][0]);
      GLDS16(Bg + kt + 64, &Bs[nb + 1][wv * 8][0]);
    }
    #pragma unroll
    for (int half = 0; half < 2; half++)
      #pragma unroll
      for (int kk = 0; kk < 2; kk++)
        #pragma unroll
        for (int i = 0; i < 2; i++)
          acc[i] = __builtin_amdgcn_mfma_f32_16x16x32_bf16(af[half][kk][i], bf[half][kk], acc[i], 0, 0, 0);
    __syncthreads();
    cur ^= 2;
  }
  int rowb = (lane >> 4) * 4, col = lane & 15;
  #pragma unroll
  for (int i = 0; i < 2; i++)
    #pragma unroll
    for (int r2 = 0; r2 < 4; r2++){
      int p = mt * 64 + wm + i * 16 + rowb + r2;
      int c = ct * 64 + wn + col;
      unsigned short o;
      if (mask[p] != 0.f) o = f2bf(acc[i][r2] * (1.f / 9.f));
      else                o = fgT[((size_t)b * L + p) * C_IN + c];
      finalT[((size_t)b * L + p) * C_IN + c] = o;
    }
}

// ---------------- K4: branch convs, 2-tap-per-barrier staging -------------------
__global__ __launch_bounds__(512) void branch_gemm(const unsigned short* __restrict__ finalT,
                                                   const unsigned short* __restrict__ Wr,
                                                   const float* __restrict__ conv_b,
                                                   const unsigned short* __restrict__ zpage,
                                                   float* __restrict__ out){
  __shared__ unsigned short As[4][64][64];   // 32 KB
  __shared__ unsigned short Bs[4][64][64];   // 32 KB
  int nwg = gridDim.x, bid = blockIdx.x;     // 512
  int nid = (bid & 7) * (nwg >> 3) + (bid >> 3);   // XCD-affine
  int bg = nid >> 4, pt = nid & 15;
  int b = bg >> 2, g = bg & 3;
  int rate = 1 << g;
  int p0 = pt * 64;
  int tid = threadIdx.x, lane = tid & 63, wv = tid >> 6;   // wv in [0,8)
  int wm = (wv & 1) * 32, wn = (wv >> 1) * 16;
  int rsel = lane & 15;
  int srow = lane >> 3;
  int scol = ((lane & 7) ^ srow) * 8;
  const unsigned short* FT = finalT + (size_t)b * L * C_IN;
  const unsigned short* WG = Wr + (size_t)(g * 9) * 64 * C_IN;

  int prow = p0 + wv * 8 + srow;
  int ayy = prow >> 5, axx = prow & 31;
  auto a_src = [&](int t) -> const unsigned short* {
    int s = t >> 2, q = t & 3;
    int dy = s / 3 - 1, dx = s - (s / 3) * 3 - 1;
    int iy = ayy + rate * dy, ix = axx + rate * dx;
    if ((unsigned)iy < HW && (unsigned)ix < HW)
      return FT + (size_t)(iy * HW + ix) * C_IN + q * 64 + scol;
    return zpage;
  };
  auto b_src = [&](int t) -> const unsigned short* {
    int s = t >> 2, q = t & 3;
    int n = wv * 8 + srow;
    return WG + (size_t)(s * 64 + n) * C_IN + q * 64 + scol;
  };

  f32x4 acc[2] = {};
  GLDS16(a_src(0), &As[0][wv * 8][0]);
  GLDS16(b_src(0), &Bs[0][wv * 8][0]);
  GLDS16(a_src(1), &As[1][wv * 8][0]);
  GLDS16(b_src(1), &Bs[1][wv * 8][0]);
  __syncthreads();
  int cur = 0;
  for (int t2 = 0; t2 < 18; ++t2){     // 2 taps per iteration (36 total)
    short8 af[2][2][2], bf[2][2];
    #pragma unroll
    for (int half = 0; half < 2; half++)
      #pragma unroll
      for (int kk = 0; kk < 2; kk++){
        int s0 = kk * 4 + (lane >> 4);
        int col = ((s0 ^ (rsel & 7)) << 3);
        #pragma unroll
        for (int i = 0; i < 2; i++)
          af[half][kk][i] = *(const short8*)&As[cur + half][wm + i * 16 + rsel][col];
        bf[half][kk] = *(const short8*)&Bs[cur + half][wn + rsel][col];
      }
    if (t2 + 1 < 18){
      int nb = cur ^ 2;
      GLDS16(a_src(2 * t2 + 2), &As[nb][wv * 8][0]);
      GLDS16(b_src(2 * t2 + 2), &Bs[nb][wv * 8][0]);
      GLDS16(a_src(2 * t2 + 3), &As[nb + 1][wv * 8][0]);
      GLDS16(b_src(2 * t2 + 3), &Bs[nb + 1][wv * 8][0]);
    }
    #pragma unroll
    for (int half = 0; half < 2; half++)
      #pragma unroll
      for (int kk = 0; kk < 2; kk++)
        #pragma unroll
        for (int i = 0; i < 2; i++)
          acc[i] = __builtin_amdgcn_mfma_f32_16x16x32_bf16(af[half][kk][i], bf[half][kk], acc[i], 0, 0, 0);
    __syncthreads();
    cur ^= 2;
  }
  int rowb = (lane >> 4) * 4, col = lane & 15;
  float* O = out + (size_t)(b * 256 + g * 64) * L;
  int n = wn + col;
  float bias = conv_b[g * 64 + n];
  #pragma unroll
  for (int i = 0; i < 2; i++)
    #pragma unroll
    for (int r2 = 0; r2 < 4; r2++){
      int p = p0 + wm + i * 16 + rowb + r2;
      O[(size_t)n * L + p] = fmaxf(acc[i][r2] + bias, 0.f);
    }
}

// ---------------- workspace layout (bytes) — round-12 layout --------------------
// [0,        16777216) : D    (8*1024*1024 bf16)
// [16777216, 35717120) : W    (8*1156*1024 bf16)
// [35717120, 52494336) : AR   (8*1024*1024 bf16)
// [52494336, 69271552) : U    (8*1024*1024 bf16)
// [69271552, 73465856) : mbgT
// [73465856, 77660160) : mbgS
// [77660160, 81854464) : finalT
// [81854464, 83034112) : Wr
// [83034112, 83427328) : psum (written unconditionally — no init)
// [83427328, 83460096) : rn
// [83460096, 83492864) : eps
// [83492864, 83493376) : zpage
// fgT lives in d_out[0 .. 4.2MB)

extern "C" void kernel_launch(void* const* d_in, const int* in_sizes, int n_in,
                              void* d_out, int out_size, void* d_ws, size_t ws_size,
                              hipStream_t stream){
  const float* fg     = (const float*)d_in[0];
  const float* mask   = (const float*)d_in[1];
  const float* bgd    = (const float*)d_in[2];
  const float* conv_w = (const float*)d_in[3];
  const float* conv_b = (const float*)d_in[4];

  char* ws = (char*)d_ws;
  unsigned short* D      = (unsigned short*)(ws + 0);
  unsigned short* W      = (unsigned short*)(ws + 16777216);
  unsigned short* AR     = (unsigned short*)(ws + 35717120);
  unsigned short* U      = (unsigned short*)(ws + 52494336);
  unsigned short* mbgT   = (unsigned short*)(ws + 69271552);
  unsigned short* mbgS   = (unsigned short*)(ws + 73465856);
  unsigned short* finalT = (unsigned short*)(ws + 77660160);
  unsigned short* Wr     = (unsigned short*)(ws + 81854464);
  float*          psum   = (float*)(ws + 83034112);
  float*          rn     = (float*)(ws + 83427328);
  float*          eps    = (float*)(ws + 83460096);
  unsigned short* zpage  = (unsigned short*)(ws + 83492864);
  unsigned short* fgT    = (unsigned short*)d_out;
  float* out = (float*)d_out;

  fused_prep<<<2816, 256, 0, stream>>>(fg, bgd, mask, fgT, mbgT, mbgS, psum,
                                       conv_w, Wr, zpage);
  gemm_d_rn<<<2064, 512, 0, stream>>>(fgT, mbgT, D, psum, rn, eps);
  box3<<<2312, 256, 0, stream>>>(D, W);
  prop_softmax_diag<<<2048, 512, 0, stream>>>(W, eps, rn, AR);
  u_stencil<<<2048, 512, 0, stream>>>(AR, U);
  gemm3_final<<<512, 512, 0, stream>>>(U, mbgS, mask, fgT, finalT);
  branch_gemm<<<512, 512, 0, stream>>>(finalT, Wr, conv_b, zpage, out);
}